// Round 8
// baseline (491.654 us; speedup 1.0000x reference)
//
#include <hip/hip_runtime.h>
#include <hip/hip_bf16.h>
#include <hip/hip_cooperative_groups.h>

namespace cg = cooperative_groups;

// Problem constants
#define BB   4
#define HH   32
#define QQ   16
#define NN   4096
#define HKV  8
#define DD   128
#define NK   3072
#define GRP  4

#define GRID 512          /* 2 blocks/CU on 256 CUs — cooperative-safe */

// k2 params (round-4-proven)
#define SPLITK2 16
#define KPB2    (NK / SPLITK2)   /* 192 */
#define KCH     64
// k4 params (round-5-proven)
#define K4SPLIT 8
#define K4LEN   (4096 / K4SPLIT) /* 512 */
#define KC4     128
#define LPAD    136              /* 128 + 8 ushort pad */

typedef __attribute__((ext_vector_type(8))) short bf16x8;
typedef __attribute__((ext_vector_type(4))) float f32x4;

__device__ __forceinline__ unsigned int pack_bf16(float lo, float hi) {
    union { unsigned int u; __hip_bfloat16 h[2]; } p;
    p.h[0] = __float2bfloat16(lo);
    p.h[1] = __float2bfloat16(hi);
    return p.u;
}

// ---------------------------------------------------------------------------
// Fused cooperative kernel: 5 phases, grid.sync() between.
//   P1 gather+norm (k1, 4 rows/block)          -> aw_out (output 2)
//   P2 ctx partial GEMM bf16 MFMA (k2 round-4) -> partial [512][64][128] bf16
//   P3 k-split reduce (k3)                     -> ctxb [64][4096] bf16
//   P4 out GEMM bf16 MFMA (k4 round-5, x2)     -> pout [8][64][4096] bf16
//   P5 k-split reduce (k5, x2)                 -> out (output 1)
// LDS: union of phase needs, 26.1 KB -> 2 blocks/CU uses 52 KB of 160 KB.
// ---------------------------------------------------------------------------
__global__ __launch_bounds__(256, 2)
void fused_pruner(const float* __restrict__ attn_w,
                  const float* __restrict__ v_cache,
                  const float* __restrict__ W,
                  const int* __restrict__ keep_idx,
                  float* __restrict__ out,
                  float* __restrict__ aw_out,
                  __hip_bfloat16* __restrict__ partial,
                  __hip_bfloat16* __restrict__ ctxb,
                  __hip_bfloat16* __restrict__ pout)
{
    cg::grid_group grid = cg::this_grid();

    __shared__ union {
        struct { float vals[NK]; float red[256]; } p1;                    // 13.3 KB
        struct { unsigned short Vt[128 * 64]; int idxs[KCH]; } p2;        // 16.6 KB
        struct { unsigned short Al[64][LPAD];
                 unsigned short Bl[32][LPAD]; } p4;                       // 26.1 KB
    } sm;

    const int bid = blockIdx.x;
    const int tid = threadIdx.x;

    // ================= P1: gather + renormalize (4 rows/block) =============
    for (int rr = 0; rr < 4; ++rr) {
        const int row = bid * 4 + rr;                  // 0..2047
        const float* src = attn_w + (size_t)row * NN;
        float* dst = aw_out + (size_t)row * NK;

        float s = 0.f;
        for (int k = tid; k < NK; k += 256) {
            float v = src[keep_idx[k]];
            sm.p1.vals[k] = v;
            s += v;
        }
        sm.p1.red[tid] = s;
        __syncthreads();
        for (int st = 128; st > 0; st >>= 1) {
            if (tid < st) sm.p1.red[tid] += sm.p1.red[tid + st];
            __syncthreads();
        }
        const float inv = 1.0f / (sm.p1.red[0] + 1e-6f);
        for (int k = tid; k < NK; k += 256)
            dst[k] = sm.p1.vals[k] * inv;
        __syncthreads();
    }
    __threadfence();
    grid.sync();

    // ================= P2: ctx partial GEMM (round-4 k2 body) ==============
    {
        const int ks  = bid & 15;
        const int hkv = (bid >> 4) & 7;
        const int b   = bid >> 7;
        const int lane = tid & 63;
        const int w    = tid >> 6;           // wave id -> M rows w*16..+15
        const int fr   = lane & 15;
        const int kg   = lane >> 4;

        const int k0 = ks * KPB2;
        const float* arow = aw_out + (size_t)((b * HH + hkv * GRP + w) * QQ + fr) * NK + k0;
        const float* vb   = v_cache + (size_t)(b * HKV + hkv) * NN * DD;

        f32x4 acc[8];
#pragma unroll
        for (int nt = 0; nt < 8; ++nt) acc[nt] = (f32x4){0.f, 0.f, 0.f, 0.f};

        const int sd  = tid & 127;
        const int sc0 = tid >> 7;            // 0..1

        for (int c = 0; c < KPB2; c += KCH) {
            __syncthreads();                       // Vt free
            if (tid < KCH) sm.p2.idxs[tid] = keep_idx[k0 + c + tid];
            __syncthreads();                       // idxs ready

#pragma unroll
            for (int p = 0; p < 4; ++p) {
                const int cs = sc0 + 2 * p;        // 16B chunk 0..7
                float v[8];
#pragma unroll
                for (int e = 0; e < 8; ++e)
                    v[e] = vb[(size_t)sm.p2.idxs[8 * cs + e] * DD + sd];
                uint4 pk;
                pk.x = pack_bf16(v[0], v[1]);
                pk.y = pack_bf16(v[2], v[3]);
                pk.z = pack_bf16(v[4], v[5]);
                pk.w = pack_bf16(v[6], v[7]);
                const int us = sd * 64 + ((cs ^ (sd & 7)) << 3);
                *reinterpret_cast<uint4*>(&sm.p2.Vt[us]) = pk;
            }
            __syncthreads();                       // Vt ready

#pragma unroll
            for (int kc = 0; kc < 2; ++kc) {
                const float* ap = arow + c + kc * 32 + kg * 8;
                const float4 a0 = *reinterpret_cast<const float4*>(ap);
                const float4 a1 = *reinterpret_cast<const float4*>(ap + 4);
                union { bf16x8 v; unsigned int u[4]; } af;
                af.u[0] = pack_bf16(a0.x, a0.y);
                af.u[1] = pack_bf16(a0.z, a0.w);
                af.u[2] = pack_bf16(a1.x, a1.y);
                af.u[3] = pack_bf16(a1.z, a1.w);

                const int cs = kc * 4 + kg;
                const int xr = (cs ^ (fr & 7)) << 3;
#pragma unroll
                for (int nt = 0; nt < 8; ++nt) {
                    const int d  = nt * 16 + fr;
                    const int us = d * 64 + xr;
                    bf16x8 bf = *reinterpret_cast<const bf16x8*>(&sm.p2.Vt[us]);
                    acc[nt] = __builtin_amdgcn_mfma_f32_16x16x32_bf16(af.v, bf, acc[nt], 0, 0, 0);
                }
            }
        }

        __hip_bfloat16* pb = partial + (size_t)bid * (64 * DD);
#pragma unroll
        for (int nt = 0; nt < 8; ++nt) {
#pragma unroll
            for (int reg = 0; reg < 4; ++reg) {
                const int row = w * 16 + kg * 4 + reg;
                pb[row * DD + nt * 16 + fr] = __float2bfloat16(acc[nt][reg]);
            }
        }
    }
    __threadfence();
    grid.sync();

    // ================= P3: reduce partials -> ctxb ==========================
#pragma unroll
    for (int i = 0; i < 2; ++i) {
        const int flat = bid * 256 + tid + i * (GRID * 256);  // bq*4096 + idx
        const int bq = flat >> 12;
        const int idx = flat & 4095;
        const int b = bq >> 4, q = bq & 15;
        const int h = idx >> 7, d = idx & 127;
        const int hkv = h >> 2, g = h & 3;
        const int r = g * 16 + q;

        const __hip_bfloat16* p = partial
            + (size_t)((b * 8 + hkv) * SPLITK2) * (64 * DD) + r * DD + d;
        float s = 0.f;
#pragma unroll
        for (int ss = 0; ss < SPLITK2; ++ss)
            s += __bfloat162float(p[(size_t)ss * (64 * DD)]);
        ctxb[flat] = __float2bfloat16(s);
    }
    __threadfence();
    grid.sync();

    // ================= P4: out GEMM (round-5 k4 body, 2 units) =============
    {
        const int lane = tid & 63;
        const int w    = tid >> 6;
        const int fr = lane & 15;
        const int kg = lane >> 4;
        const unsigned short* ctxu = reinterpret_cast<const unsigned short*>(ctxb);

#pragma unroll
        for (int uu = 0; uu < 2; ++uu) {
            const int u  = bid + uu * GRID;    // 0..1023
            const int nt = u >> 3;             // 0..127
            const int ks = u & 7;
            const int kbase = ks * K4LEN;

            f32x4 acc0 = {0.f, 0.f, 0.f, 0.f};
            f32x4 acc1 = {0.f, 0.f, 0.f, 0.f};

            for (int ch = 0; ch < K4LEN / KC4; ++ch) {
                const int kb = kbase + ch * KC4;
                __syncthreads();

                {
                    const int cc = tid & 15;
                    const int r0 = tid >> 4;
#pragma unroll
                    for (int p = 0; p < 4; ++p) {
                        const int r = r0 + p * 16;
                        float4 v = *reinterpret_cast<const float4*>(
                            ctxu + (size_t)r * 4096 + kb + cc * 8);
                        *reinterpret_cast<float4*>(&sm.p4.Al[r][cc * 8]) = v;
                    }
                }
                {
                    const int cc = tid & 31;
                    const int r0 = tid >> 5;
#pragma unroll
                    for (int p = 0; p < 4; ++p) {
                        const int r = r0 + p * 8;
                        float4 v = *reinterpret_cast<const float4*>(
                            W + (size_t)(nt * 32 + r) * 4096 + kb + cc * 4);
                        union { ushort4 u4; __hip_bfloat16 h[4]; } pk;
                        pk.h[0] = __float2bfloat16(v.x);
                        pk.h[1] = __float2bfloat16(v.y);
                        pk.h[2] = __float2bfloat16(v.z);
                        pk.h[3] = __float2bfloat16(v.w);
                        *reinterpret_cast<ushort4*>(&sm.p4.Bl[r][cc * 4]) = pk.u4;
                    }
                }
                __syncthreads();

#pragma unroll
                for (int kst = 0; kst < KC4 / 32; ++kst) {
                    const int ko = kst * 32 + kg * 8;
                    bf16x8 a  = *reinterpret_cast<const bf16x8*>(&sm.p4.Al[w * 16 + fr][ko]);
                    bf16x8 b0 = *reinterpret_cast<const bf16x8*>(&sm.p4.Bl[fr][ko]);
                    bf16x8 b1 = *reinterpret_cast<const bf16x8*>(&sm.p4.Bl[16 + fr][ko]);
                    acc0 = __builtin_amdgcn_mfma_f32_16x16x32_bf16(a, b0, acc0, 0, 0, 0);
                    acc1 = __builtin_amdgcn_mfma_f32_16x16x32_bf16(a, b1, acc1, 0, 0, 0);
                }
            }

            __hip_bfloat16* pb = pout + (size_t)ks * (64 * 4096);
#pragma unroll
            for (int reg = 0; reg < 4; ++reg) {
                const int row = w * 16 + kg * 4 + reg;
                pb[(size_t)row * 4096 + nt * 32 + fr]      = __float2bfloat16(acc0[reg]);
                pb[(size_t)row * 4096 + nt * 32 + 16 + fr] = __float2bfloat16(acc1[reg]);
            }
            __syncthreads();
        }
    }
    __threadfence();
    grid.sync();

    // ================= P5: reduce pout -> out ==============================
#pragma unroll
    for (int i = 0; i < 2; ++i) {
        const int flat = bid * 256 + tid + i * (GRID * 256);
        float s = 0.f;
#pragma unroll
        for (int ss = 0; ss < K4SPLIT; ++ss)
            s += __bfloat162float(pout[(size_t)ss * (64 * 4096) + flat]);
        out[flat] = s;
    }
}

// ---------------------------------------------------------------------------
extern "C" void kernel_launch(void* const* d_in, const int* in_sizes, int n_in,
                              void* d_out, int out_size, void* d_ws, size_t ws_size,
                              hipStream_t stream)
{
    const float* attn_w  = (const float*)d_in[0];   // [4][32][16][4096]
    const float* v_cache = (const float*)d_in[1];   // [4][8][4096][128]
    const float* o_proj  = (const float*)d_in[2];   // [4096][4096]
    const int*   keep_idx = (const int*)d_in[3];    // [3072]

    float* out    = (float*)d_out;                  // [4][16][4096] = 262144
    float* aw_out = (float*)d_out + 262144;         // [4][32][16][3072]

    // ws layout (bytes):
    //   [0, 8 MB)       : P2 bf16 partial [512][64][128]  -- dead after P3
    //   [0, 4 MB)       : P4 bf16 pout [8][64][4096]      -- reuses region
    //   [8 MB, 8.5 MB)  : ctx bf16 [64][4096]
    __hip_bfloat16* partial2 = (__hip_bfloat16*)d_ws;
    __hip_bfloat16* ctxb = (__hip_bfloat16*)((char*)d_ws + (size_t)8 * 1024 * 1024);
    __hip_bfloat16* pout = (__hip_bfloat16*)d_ws;

    void* args[] = { (void*)&attn_w, (void*)&v_cache, (void*)&o_proj,
                     (void*)&keep_idx, (void*)&out, (void*)&aw_out,
                     (void*)&partial2, (void*)&ctxb, (void*)&pout };
    hipLaunchCooperativeKernel((const void*)fused_pruner,
                               dim3(GRID), dim3(256), args, 0, stream);
}

// Round 9
// 80.773 us; speedup vs baseline: 6.0869x; 6.0869x over previous
//
#include <hip/hip_runtime.h>
#include <hip/hip_bf16.h>

// Problem constants
#define BB   4
#define HH   32
#define QQ   16
#define NN   4096
#define HKV  8
#define DD   128
#define NK   3072
#define GRP  4

typedef __attribute__((ext_vector_type(8))) short bf16x8;
typedef __attribute__((ext_vector_type(4))) float f32x4;

__device__ __forceinline__ unsigned int pack_bf16(float lo, float hi) {
    union { unsigned int u; __hip_bfloat16 h[2]; } p;
    p.h[0] = __float2bfloat16(lo);
    p.h[1] = __float2bfloat16(hi);
    return p.u;
}

// ---------------------------------------------------------------------------
// Kernel 1 (round-5 verbatim): gather + renormalize; writes aw f32 (output 2)
// and a bf16 copy for k2's A-operand. grid = 2048 blocks, 256 threads.
// ---------------------------------------------------------------------------
__global__ __launch_bounds__(256)
void k1_gather_norm(const float* __restrict__ attn_w,
                    const int* __restrict__ keep_idx,
                    float* __restrict__ aw_out,
                    __hip_bfloat16* __restrict__ aw16)
{
    const int row = blockIdx.x;                 // (b*H + h)*Q + q
    const float* src = attn_w + (size_t)row * NN;
    float* dst = aw_out + (size_t)row * NK;
    unsigned int* dst16 = reinterpret_cast<unsigned int*>(aw16 + (size_t)row * NK);

    __shared__ float vals[NK];
    __shared__ float red[256];

    float s = 0.f;
    for (int k = threadIdx.x; k < NK; k += 256) {
        float v = src[keep_idx[k]];
        vals[k] = v;
        s += v;
    }
    red[threadIdx.x] = s;
    __syncthreads();
    for (int st = 128; st > 0; st >>= 1) {
        if (threadIdx.x < st) red[threadIdx.x] += red[threadIdx.x + st];
        __syncthreads();
    }
    const float inv = 1.0f / (red[0] + 1e-6f);
    for (int k = threadIdx.x * 2; k < NK; k += 512) {
        float a = vals[k] * inv;
        float b = vals[k + 1] * inv;
        *reinterpret_cast<float2*>(&dst[k]) = make_float2(a, b);
        dst16[k >> 1] = pack_bf16(a, b);
    }
}

// ---------------------------------------------------------------------------
// Kernel 2' : ctx GEMM, in-block split-K, writes ctxb directly (no partials).
// grid = 32 (b,hkv) tiles * 8 d-slices = 256 blocks, 512 thr = 8 waves.
// Wave (mw = w&3, kh = w>>2): M-rows mw*16..+15, N = block's 16 d-cols,
// K-half kh*1536..+1535 in 24 chunks of 64.
//   A: bf16x8 per-lane loads from aw16 (L3-hot; rows wave-exclusive).
//   B: gathered V chunk staged transposed [kh][16 d][64 k] bf16, XOR swizzle
//      us(kh,d,k) = kh*1024 + d*64 + (((k>>3)^(d&7))<<3) + (k&7)  [ushorts].
//      Staging coverage: units (kh,d,cs2) = 2*16*16 = 512 = exactly 512 thr,
//      one uint2 (4 k-elems) each. idxs[2][64]: 128 loads, tid<128.
// Epilogue: kh=1 waves deposit acc in Rt[4][16][16]; kh=0 waves add + write
// ctxb[bq][i] bf16 (bq = b*16+q, i = (hkv*4+mw)*128 + ds*16 + fr).
// ---------------------------------------------------------------------------
#define KH2  1536
#define KCH  64

__global__ __launch_bounds__(512, 2)
void k2_ctx(const __hip_bfloat16* __restrict__ aw16,
            const float* __restrict__ v_cache,
            const int* __restrict__ keep_idx,
            __hip_bfloat16* __restrict__ ctxb)
{
    const int bid = blockIdx.x;          // tile*8 + ds
    const int ds  = bid & 7;
    const int hkv = (bid >> 3) & 7;
    const int b   = bid >> 6;
    const int tid = threadIdx.x;
    const int lane = tid & 63;
    const int w    = tid >> 6;           // 0..7
    const int mw   = w & 3;              // M-group (head g = mw)
    const int kh   = w >> 2;             // K-half
    const int fr   = lane & 15;
    const int kg   = lane >> 4;

    __shared__ unsigned short Vt[2 * 16 * 64];   // 4 KB, swizzled [kh][d][k]
    __shared__ int idxs[2][KCH];
    __shared__ float Rt[4][16][16];              // 4 KB reduce buffer

    // A row for this lane: global aw row = (b*32 + hkv*4 + mw)*16 + fr
    const unsigned short* arow = reinterpret_cast<const unsigned short*>(aw16)
        + (size_t)((b * HH + hkv * GRP + mw) * QQ + fr) * NK + kh * KH2;
    const float* vb = v_cache + (size_t)(b * HKV + hkv) * NN * DD + ds * 16;

    f32x4 acc = {0.f, 0.f, 0.f, 0.f};

    // staging ids: unit = tid -> (skh, scs2, sd); 512 units = full 2x16x64 tile
    const int sd   = tid & 15;           // d within slice
    const int scs2 = (tid >> 4) & 15;    // 8B chunk (4 k-elems) 0..15
    const int skh  = tid >> 8;           // half

    for (int c = 0; c < KH2; c += KCH) {
        __syncthreads();                       // Vt/idxs free (prev compute done)
        if (tid < 128)
            idxs[tid >> 6][tid & 63] = keep_idx[(tid >> 6) * KH2 + c + (tid & 63)];
        __syncthreads();                       // idxs ready

        {   // stage both halves' V chunks: 4 gathered loads + one 8B write
            const int kbase = scs2 * 4;        // k = kbase..kbase+3
            float v0 = vb[(size_t)idxs[skh][kbase + 0] * DD + sd];
            float v1 = vb[(size_t)idxs[skh][kbase + 1] * DD + sd];
            float v2 = vb[(size_t)idxs[skh][kbase + 2] * DD + sd];
            float v3 = vb[(size_t)idxs[skh][kbase + 3] * DD + sd];
            uint2 pk;
            pk.x = pack_bf16(v0, v1);
            pk.y = pack_bf16(v2, v3);
            const int us = skh * 1024 + sd * 64
                         + (((scs2 >> 1) ^ (sd & 7)) << 3) + ((scs2 & 1) << 2);
            *reinterpret_cast<uint2*>(&Vt[us]) = pk;
        }
        __syncthreads();                       // Vt ready

#pragma unroll
        for (int kc = 0; kc < 2; ++kc) {
            bf16x8 af = *reinterpret_cast<const bf16x8*>(arow + c + kc * 32 + kg * 8);
            const int cs = kc * 4 + kg;        // 16B chunk along k
            const int us = kh * 1024 + fr * 64 + ((cs ^ (fr & 7)) << 3);
            bf16x8 bf = *reinterpret_cast<const bf16x8*>(&Vt[us]);
            acc = __builtin_amdgcn_mfma_f32_16x16x32_bf16(af, bf, acc, 0, 0, 0);
        }
    }

    // in-block K-half reduce, then write ctxb
    __syncthreads();
    if (kh == 1) {
#pragma unroll
        for (int reg = 0; reg < 4; ++reg)
            Rt[mw][kg * 4 + reg][fr] = acc[reg];
    }
    __syncthreads();
    if (kh == 0) {
#pragma unroll
        for (int reg = 0; reg < 4; ++reg) {
            const float f = acc[reg] + Rt[mw][kg * 4 + reg][fr];
            const int q  = kg * 4 + reg;
            const int bq = b * QQ + q;
            const int i  = (hkv * GRP + mw) * DD + ds * 16 + fr;
            ctxb[(size_t)bq * 4096 + i] = __float2bfloat16(f);
        }
    }
}

// ---------------------------------------------------------------------------
// Kernel 4' : out = ctx @ W^T, in-block split-K, writes out f32 directly.
// grid = 256 N-tiles (16 o-cols each), 512 thr = 8 waves = 4 mw x 2 kh.
// Per iter i (16 iters): stage A[2][64][128] bf16 from ctxb and
// B[2][16][128] bf16 (f32->cvt) from W, both halves; wave (mw,kh) runs
// 4 MFMAs on its half. LPAD=136 rows (proven 0-conflict pattern).
// Staging coverage: A units (ah,r,c8) = 2*64*16 = 2048 = 512 thr x 4 passes;
// B units (bh,r,cc) = 2*16*32 = 1024 = 512 thr x 2 passes.
// Epilogue: kh-pair reduce via Rt, write out (64B-contiguous f32).
// ---------------------------------------------------------------------------
#define KH4  2048
#define KC4  128
#define LPAD 136

__global__ __launch_bounds__(512, 2)
void k4_gemm(const __hip_bfloat16* __restrict__ ctxb,
             const float* __restrict__ W,
             float* __restrict__ out)
{
    const int nt  = blockIdx.x;        // o-cols nt*16 .. nt*16+15
    const int tid = threadIdx.x;
    const int lane = tid & 63;
    const int w    = tid >> 6;
    const int mw   = w & 3;            // M-rows mw*16..+15
    const int kh   = w >> 2;           // K-half
    const int fr   = lane & 15;
    const int kg   = lane >> 4;

    __shared__ unsigned short Al[2][64][LPAD];   // 34.8 KB
    __shared__ unsigned short Bl[2][16][LPAD];   //  8.7 KB
    __shared__ float Rt[4][16][16];              //  4.0 KB

    const unsigned short* ctxu = reinterpret_cast<const unsigned short*>(ctxb);
    f32x4 acc = {0.f, 0.f, 0.f, 0.f};

    for (int i = 0; i < 16; ++i) {
        __syncthreads();

        // stage A: 2048 bf16x8 units
#pragma unroll
        for (int p = 0; p < 4; ++p) {
            const int u  = tid + 512 * p;
            const int c8 = u & 15;
            const int r  = (u >> 4) & 63;
            const int ah = u >> 10;
            *reinterpret_cast<float4*>(&Al[ah][r][c8 * 8]) =
                *reinterpret_cast<const float4*>(
                    ctxu + (size_t)r * 4096 + ah * KH4 + i * KC4 + c8 * 8);
        }
        // stage B: 1024 float4 units, f32 -> bf16
#pragma unroll
        for (int p = 0; p < 2; ++p) {
            const int u  = tid + 512 * p;
            const int cc = u & 31;
            const int r  = (u >> 5) & 15;
            const int bh = u >> 9;
            float4 v = *reinterpret_cast<const float4*>(
                W + (size_t)(nt * 16 + r) * 4096 + bh * KH4 + i * KC4 + cc * 4);
            union { ushort4 u4; __hip_bfloat16 h[4]; } pk;
            pk.h[0] = __float2bfloat16(v.x);
            pk.h[1] = __float2bfloat16(v.y);
            pk.h[2] = __float2bfloat16(v.z);
            pk.h[3] = __float2bfloat16(v.w);
            *reinterpret_cast<ushort4*>(&Bl[bh][r][cc * 4]) = pk.u4;
        }
        __syncthreads();

#pragma unroll
        for (int kc = 0; kc < 4; ++kc) {
            const int ko = kc * 32 + kg * 8;
            bf16x8 a  = *reinterpret_cast<const bf16x8*>(&Al[kh][mw * 16 + fr][ko]);
            bf16x8 bv = *reinterpret_cast<const bf16x8*>(&Bl[kh][fr][ko]);
            acc = __builtin_amdgcn_mfma_f32_16x16x32_bf16(a, bv, acc, 0, 0, 0);
        }
    }

    // in-block K-half reduce, write out f32
    __syncthreads();
    if (kh == 1) {
#pragma unroll
        for (int reg = 0; reg < 4; ++reg)
            Rt[mw][kg * 4 + reg][fr] = acc[reg];
    }
    __syncthreads();
    if (kh == 0) {
#pragma unroll
        for (int reg = 0; reg < 4; ++reg) {
            const int bq = mw * 16 + kg * 4 + reg;
            out[(size_t)bq * 4096 + nt * 16 + fr] = acc[reg] + Rt[mw][kg * 4 + reg][fr];
        }
    }
}

// ---------------------------------------------------------------------------
extern "C" void kernel_launch(void* const* d_in, const int* in_sizes, int n_in,
                              void* d_out, int out_size, void* d_ws, size_t ws_size,
                              hipStream_t stream)
{
    const float* attn_w  = (const float*)d_in[0];   // [4][32][16][4096]
    const float* v_cache = (const float*)d_in[1];   // [4][8][4096][128]
    const float* o_proj  = (const float*)d_in[2];   // [4096][4096]
    const int*   keep_idx = (const int*)d_in[3];    // [3072]

    float* out    = (float*)d_out;                  // [4][16][4096] = 262144
    float* aw_out = (float*)d_out + 262144;         // [4][32][16][3072]

    // ws layout (bytes):
    //   [0, 0.5 MB)   : ctxb bf16 [64][4096]
    //   [1 MB, 13 MB) : aw16 bf16 copy (6,291,456 bf16)
    __hip_bfloat16* ctxb = (__hip_bfloat16*)d_ws;
    __hip_bfloat16* aw16 = (__hip_bfloat16*)((char*)d_ws + (size_t)1 * 1024 * 1024);

    k1_gather_norm<<<BB * HH * QQ, 256, 0, stream>>>(attn_w, keep_idx, aw_out, aw16);
    k2_ctx<<<256, 512, 0, stream>>>(aw16, v_cache, keep_idx, ctxb);
    k4_gemm<<<256, 512, 0, stream>>>(ctxb, o_proj, out);
}

// Round 10
// 60.065 us; speedup vs baseline: 8.1854x; 1.3448x over previous
//
#include <hip/hip_runtime.h>
#include <hip/hip_bf16.h>

// Problem constants
#define BB   4
#define HH   32
#define QQ   16
#define NN   4096
#define HKV  8
#define DD   128
#define NK   3072
#define GRP  4

typedef __attribute__((ext_vector_type(8))) short bf16x8;
typedef __attribute__((ext_vector_type(4))) float f32x4;

__device__ __forceinline__ unsigned int pack_bf16(float lo, float hi) {
    union { unsigned int u; __hip_bfloat16 h[2]; } p;
    p.h[0] = __float2bfloat16(lo);
    p.h[1] = __float2bfloat16(hi);
    return p.u;
}

__device__ __forceinline__ void atomAddF32(float* p, float v) {
    unsafeAtomicAdd(p, v);   // native global_atomic_add_f32, device scope
}

// ---------------------------------------------------------------------------
// Kernel 1: gather + renormalize -> aw f32 (output 2) + bf16 copy for k2.
// Also zeroes ctxf (1 MB) and out (1 MB): flat = bid*256+tid covers
// 2048*256 = 524288 = 262144 (ctxf) + 262144 (out) exactly.
// grid = 2048 blocks, 256 threads.
// ---------------------------------------------------------------------------
__global__ __launch_bounds__(256)
void k1_gather_norm(const float* __restrict__ attn_w,
                    const int* __restrict__ keep_idx,
                    float* __restrict__ aw_out,
                    __hip_bfloat16* __restrict__ aw16,
                    float* __restrict__ ctxf,
                    float* __restrict__ out)
{
    const int row = blockIdx.x;                 // (b*H + h)*Q + q
    const float* src = attn_w + (size_t)row * NN;
    float* dst = aw_out + (size_t)row * NK;
    unsigned int* dst16 = reinterpret_cast<unsigned int*>(aw16 + (size_t)row * NK);

    // zero the atomic accumulation buffers (1 element of each half per thread)
    {
        const int flat = blockIdx.x * 256 + threadIdx.x;   // 0..524287
        if (flat < 262144) ctxf[flat] = 0.f;
        else               out[flat - 262144] = 0.f;
    }

    __shared__ float vals[NK];
    __shared__ float red[256];

    float s = 0.f;
    for (int k = threadIdx.x; k < NK; k += 256) {
        float v = src[keep_idx[k]];
        vals[k] = v;
        s += v;
    }
    red[threadIdx.x] = s;
    __syncthreads();
    for (int st = 128; st > 0; st >>= 1) {
        if (threadIdx.x < st) red[threadIdx.x] += red[threadIdx.x + st];
        __syncthreads();
    }
    const float inv = 1.0f / (red[0] + 1e-6f);
    for (int k = threadIdx.x * 2; k < NK; k += 512) {
        float a = vals[k] * inv;
        float b = vals[k + 1] * inv;
        *reinterpret_cast<float2*>(&dst[k]) = make_float2(a, b);
        dst16[k >> 1] = pack_bf16(a, b);
    }
}

// ---------------------------------------------------------------------------
// Kernel 2 (round-5 body): ctx partial GEMM via bf16 MFMA; epilogue now
// atomically accumulates f32 into ctxf (no partial buffer, no k3).
// grid = B*HKV*SPLITK2 = 512 blocks, 512 threads (8 waves).
// Wave w: mw = w&3 (M rows mw*16..+15), nh = w>>2 (d-half).
//   B: gathered V staged transposed into LDS Vt[d][k] bf16, XOR chunk swizzle
//      us(d,cs) = d*64 + ((cs ^ (d&7))<<3), cs = 16B chunk (8 k) 0..7.
//      Coverage: unit=(d,cs) -> 128*8 = 1024 units = 2 passes x 512 threads.
// ---------------------------------------------------------------------------
#define SPLITK2 16
#define KPB2    (NK / SPLITK2)   /* 192 */
#define KCH     64

__global__ __launch_bounds__(512, 4)
void k2_ctx(const __hip_bfloat16* __restrict__ aw16,
            const float* __restrict__ v_cache,
            const int* __restrict__ keep_idx,
            float* __restrict__ ctxf)
{
    const int bid = blockIdx.x;          // ((b*8+hkv)*16 + ks)
    const int ks  = bid & 15;
    const int hkv = (bid >> 4) & 7;
    const int b   = bid >> 7;
    const int tid = threadIdx.x;
    const int lane = tid & 63;
    const int w    = tid >> 6;           // wave id 0..7
    const int mw   = w & 3;              // M-group: rows mw*16..+15
    const int nh   = w >> 2;             // d-half: tiles nh*4..nh*4+3
    const int fr   = lane & 15;          // fragment row/col
    const int kg   = lane >> 4;          // k-group (8 bf16)

    __shared__ unsigned short Vt[128 * 64];   // 16 KB, swizzled [d][k]
    __shared__ int idxs[KCH];

    const int k0 = ks * KPB2;
    // A row for this lane: global aw row = (b*32 + hkv*4 + mw)*16 + fr
    const unsigned short* arow = reinterpret_cast<const unsigned short*>(aw16)
        + (size_t)((b * HH + hkv * GRP + mw) * QQ + fr) * NK + k0;
    const float* vb = v_cache + (size_t)(b * HKV + hkv) * NN * DD;

    f32x4 acc[4];
#pragma unroll
    for (int nt = 0; nt < 4; ++nt) acc[nt] = (f32x4){0.f, 0.f, 0.f, 0.f};

    // staging: pass p, thread t -> unit u = t + 512p; d = u&127, cs = u>>7
    const int sd  = tid & 127;
    const int sc0 = tid >> 7;            // 0..3

    for (int c = 0; c < KPB2; c += KCH) {
        __syncthreads();                       // Vt free (prev compute done)
        if (tid < KCH) idxs[tid] = keep_idx[k0 + c + tid];
        __syncthreads();                       // idxs ready

        // stage 64 gathered V rows, transposed + swizzled, bf16.
#pragma unroll
        for (int p = 0; p < 2; ++p) {
            const int cs = sc0 + 4 * p;        // 16B chunk 0..7 (k = 8cs..8cs+7)
            float v[8];
#pragma unroll
            for (int e = 0; e < 8; ++e)
                v[e] = vb[(size_t)idxs[8 * cs + e] * DD + sd];
            uint4 pk;
            pk.x = pack_bf16(v[0], v[1]);
            pk.y = pack_bf16(v[2], v[3]);
            pk.z = pack_bf16(v[4], v[5]);
            pk.w = pack_bf16(v[6], v[7]);
            const int us = sd * 64 + ((cs ^ (sd & 7)) << 3);
            *reinterpret_cast<uint4*>(&Vt[us]) = pk;
        }
        __syncthreads();                       // Vt ready

        // compute: 2 MFMA k-steps of 32, 4 N-tiles (this wave's d-half)
#pragma unroll
        for (int kc = 0; kc < 2; ++kc) {
            bf16x8 af = *reinterpret_cast<const bf16x8*>(arow + c + kc * 32 + kg * 8);
            const int cs = kc * 4 + kg;        // 16B chunk index along k
            const int xr = (cs ^ (fr & 7)) << 3;
#pragma unroll
            for (int nt = 0; nt < 4; ++nt) {
                const int d  = (nh * 4 + nt) * 16 + fr;
                const int us = d * 64 + xr;    // (d&7) == (fr&7)
                bf16x8 bf = *reinterpret_cast<const bf16x8*>(&Vt[us]);
                acc[nt] = __builtin_amdgcn_mfma_f32_16x16x32_bf16(af, bf, acc[nt], 0, 0, 0);
            }
        }
    }

    // epilogue: atomic f32 accumulate into ctxf[bq][i], i = (hkv*4+g)*128 + d
    // C/D layout col=lane&15 (d within tile), row=(lane>>4)*4+reg -> q
#pragma unroll
    for (int nt = 0; nt < 4; ++nt) {
#pragma unroll
        for (int reg = 0; reg < 4; ++reg) {
            const int q  = kg * 4 + reg;
            const int d  = (nh * 4 + nt) * 16 + fr;
            atomAddF32(&ctxf[(size_t)(b * QQ + q) * 4096
                             + (hkv * GRP + mw) * DD + d], acc[nt][reg]);
        }
    }
}

// ---------------------------------------------------------------------------
// Kernel 4: out = ctx @ W^T via bf16 MFMA, M=64 x N=4096 x K=4096.
// grid = 128 N-tiles (32 o-cols) * 8 k-splits = 1024 blocks, 256 threads.
// A staged from f32 ctxf (cvt to bf16 in-stage, 2048 float4 units = 8 passes);
// epilogue atomically accumulates f32 into out (no pout, no k5).
// ---------------------------------------------------------------------------
#define K4SPLIT 8
#define K4LEN   (4096 / K4SPLIT)  /* 512 */
#define KC4     128
#define LPAD    136               /* 128 + 8 ushort pad */

__global__ __launch_bounds__(256, 4)
void k4_gemm(const float* __restrict__ ctxf,
             const float* __restrict__ W,
             float* __restrict__ out)
{
    const int nt  = blockIdx.x >> 3;   // 0..127  (o-cols nt*32 .. nt*32+31)
    const int ks  = blockIdx.x & 7;
    const int tid = threadIdx.x;
    const int lane = tid & 63;
    const int w    = tid >> 6;         // wave id: M-rows w*16 .. w*16+15

    __shared__ unsigned short Al[64][LPAD];   // ctx bf16 tile
    __shared__ unsigned short Bl[32][LPAD];   // W   bf16 tile

    f32x4 acc0 = {0.f, 0.f, 0.f, 0.f};
    f32x4 acc1 = {0.f, 0.f, 0.f, 0.f};

    const int kbase = ks * K4LEN;
    const int fr = lane & 15;          // fragment row/col
    const int kg = lane >> 4;          // k-group (8 bf16 each)

    for (int ch = 0; ch < K4LEN / KC4; ++ch) {
        const int kb = kbase + ch * KC4;
        __syncthreads();

        // stage A: 64 rows x 128 f32 -> bf16; units (r,cc)=64*32=2048, 8 passes
#pragma unroll
        for (int p = 0; p < 8; ++p) {
            const int u  = tid + 256 * p;
            const int cc = u & 31;
            const int r  = u >> 5;
            float4 v = *reinterpret_cast<const float4*>(
                ctxf + (size_t)r * 4096 + kb + cc * 4);
            union { ushort4 u4; __hip_bfloat16 h[4]; } pk;
            pk.h[0] = __float2bfloat16(v.x);
            pk.h[1] = __float2bfloat16(v.y);
            pk.h[2] = __float2bfloat16(v.z);
            pk.h[3] = __float2bfloat16(v.w);
            *reinterpret_cast<ushort4*>(&Al[r][cc * 4]) = pk.u4;
        }
        // stage B: 32 rows x 128 f32 -> bf16; units (r,cc)=32*32=1024, 4 passes
#pragma unroll
        for (int p = 0; p < 4; ++p) {
            const int u  = tid + 256 * p;
            const int cc = u & 31;
            const int r  = u >> 5;
            float4 v = *reinterpret_cast<const float4*>(
                W + (size_t)(nt * 32 + r) * 4096 + kb + cc * 4);
            union { ushort4 u4; __hip_bfloat16 h[4]; } pk;
            pk.h[0] = __float2bfloat16(v.x);
            pk.h[1] = __float2bfloat16(v.y);
            pk.h[2] = __float2bfloat16(v.z);
            pk.h[3] = __float2bfloat16(v.w);
            *reinterpret_cast<ushort4*>(&Bl[r][cc * 4]) = pk.u4;
        }
        __syncthreads();

#pragma unroll
        for (int kst = 0; kst < KC4 / 32; ++kst) {
            const int ko = kst * 32 + kg * 8;
            bf16x8 a  = *reinterpret_cast<const bf16x8*>(&Al[w * 16 + fr][ko]);
            bf16x8 b0 = *reinterpret_cast<const bf16x8*>(&Bl[fr][ko]);
            bf16x8 b1 = *reinterpret_cast<const bf16x8*>(&Bl[16 + fr][ko]);
            acc0 = __builtin_amdgcn_mfma_f32_16x16x32_bf16(a, b0, acc0, 0, 0, 0);
            acc1 = __builtin_amdgcn_mfma_f32_16x16x32_bf16(a, b1, acc1, 0, 0, 0);
        }
    }

    // epilogue: atomic f32 accumulate into out; C/D col=lane&15,
    // row=(lane>>4)*4+reg
#pragma unroll
    for (int reg = 0; reg < 4; ++reg) {
        const int row = w * 16 + kg * 4 + reg;
        atomAddF32(&out[(size_t)row * 4096 + nt * 32 + fr],      acc0[reg]);
        atomAddF32(&out[(size_t)row * 4096 + nt * 32 + 16 + fr], acc1[reg]);
    }
}

// ---------------------------------------------------------------------------
extern "C" void kernel_launch(void* const* d_in, const int* in_sizes, int n_in,
                              void* d_out, int out_size, void* d_ws, size_t ws_size,
                              hipStream_t stream)
{
    const float* attn_w  = (const float*)d_in[0];   // [4][32][16][4096]
    const float* v_cache = (const float*)d_in[1];   // [4][8][4096][128]
    const float* o_proj  = (const float*)d_in[2];   // [4096][4096]
    const int*   keep_idx = (const int*)d_in[3];    // [3072]

    float* out    = (float*)d_out;                  // [4][16][4096] = 262144
    float* aw_out = (float*)d_out + 262144;         // [4][32][16][3072]

    // ws layout (bytes):
    //   [0, 1 MB)     : ctxf f32 [64][4096] (atomic accum, zeroed by k1)
    //   [1 MB, 13 MB) : aw16 bf16 copy (6,291,456 bf16)
    float* ctxf = (float*)d_ws;
    __hip_bfloat16* aw16 = (__hip_bfloat16*)((char*)d_ws + (size_t)1 * 1024 * 1024);

    k1_gather_norm<<<BB * HH * QQ, 256, 0, stream>>>(attn_w, keep_idx, aw_out,
                                                     aw16, ctxf, out);
    k2_ctx<<<BB * HKV * SPLITK2, 512, 0, stream>>>(aw16, v_cache, keep_idx, ctxf);
    k4_gemm<<<128 * K4SPLIT, 256, 0, stream>>>(ctxf, o_proj, out);
}